// Round 7
// baseline (398.135 us; speedup 1.0000x reference)
//
#include <hip/hip_runtime.h>
#include <hip/hip_bf16.h>
#include <stdint.h>

// ---------------------------------------------------------------------------
// Attention block, B=4 N=2048 C=1024 H=16 D=64, bf16 MFMA pipeline:
//   cvt(x,w*) -> gemm_bt(QKV fused, Q scaled by 0.125*log2e) -> flash attn v4
//   (32x32x16 swapped-operand, lane-local softmax, swizzled V^T) -> gemm_bt(+bias)
// ---------------------------------------------------------------------------

#define GAS __attribute__((address_space(1)))
#define LAS __attribute__((address_space(3)))

typedef __attribute__((ext_vector_type(8)))  short v8s;    // 8 x bf16
typedef __attribute__((ext_vector_type(4)))  float v4f;
typedef __attribute__((ext_vector_type(16))) float v16f;   // 32x32 accum

__device__ __forceinline__ unsigned short f2bf(float f) {
  __hip_bfloat16 h = __float2bfloat16(f);
  return __builtin_bit_cast(unsigned short, h);
}

__device__ __forceinline__ float fexp2(float x) {
#if __has_builtin(__builtin_amdgcn_exp2f)
  return __builtin_amdgcn_exp2f(x);
#else
  return __expf(x * 0.6931471805599453f);
#endif
}

__device__ __forceinline__ unsigned cvtpk(float lo, float hi) {
  unsigned r;
  asm("v_cvt_pk_bf16_f32 %0, %1, %2" : "=v"(r) : "v"(lo), "v"(hi));
  return r;
}

__device__ __forceinline__ void gld_lds16(const void* g, void* l) {
  __builtin_amdgcn_global_load_lds((GAS void*)(uintptr_t)g,
                                   (LAS void*)(uint32_t)(uintptr_t)l,
                                   16, 0, 0);
}

// ---------------------------------------------------------------------------
__global__ void cvt_f32_bf16(const float* __restrict__ src,
                             unsigned short* __restrict__ dst, int n4) {
  int i = blockIdx.x * blockDim.x + threadIdx.x;
  const int stride = gridDim.x * blockDim.x;
  for (; i < n4; i += stride) {
    float4 f = ((const float4*)src)[i];
    ushort4 u;
    u.x = f2bf(f.x); u.y = f2bf(f.y); u.z = f2bf(f.z); u.w = f2bf(f.w);
    ((ushort4*)dst)[i] = u;
  }
}

// ---------------------------------------------------------------------------
// C[m][o] = sum_c A[m][c] * B[o][c]  (B^T layout). 128x128 tile, BK=64.
template<int OUTMODE>
__global__ __launch_bounds__(256)
void gemm_bt(const unsigned short* __restrict__ A,
             const unsigned short* __restrict__ Bm,
             void* __restrict__ Cout, const float* __restrict__ bias,
             int M, int N, int K, int scaleCols, float scaleVal)
{
  __shared__ unsigned short sA[128 * 64];
  __shared__ unsigned short sB[128 * 64];

  const int tid  = threadIdx.x;
  const int lane = tid & 63;
  const int w    = tid >> 6;
  const int g    = lane >> 4;
  const int r16  = lane & 15;
  const long bm  = (long)blockIdx.y * 128;
  const long bn  = (long)blockIdx.x * 128;
  const int  wm  = (w >> 1) * 64;
  const int  wn  = (w & 1) * 64;

  v4f acc[4][4] = {};

  for (int k0 = 0; k0 < K; k0 += 64) {
    #pragma unroll
    for (int t4 = 0; t4 < 4; ++t4) {
      const int t   = t4 * 4 + w;
      const int row = t * 8 + (lane >> 3);
      const long co = (long)k0 + (lane & 7) * 8;
      gld_lds16(A  + (bm + row) * K + co, (char*)sA + t * 1024);
      gld_lds16(Bm + (bn + row) * K + co, (char*)sB + t * 1024);
    }
    __syncthreads();

    v8s af[4][2], bf[4][2];
    #pragma unroll
    for (int m = 0; m < 4; ++m)
      #pragma unroll
      for (int kk = 0; kk < 2; ++kk)
        af[m][kk] = *(const v8s*)(sA + (wm + m*16 + r16)*64 + kk*32 + g*8);
    #pragma unroll
    for (int n = 0; n < 4; ++n)
      #pragma unroll
      for (int kk = 0; kk < 2; ++kk)
        bf[n][kk] = *(const v8s*)(sB + (wn + n*16 + r16)*64 + kk*32 + g*8);
    #pragma unroll
    for (int kk = 0; kk < 2; ++kk)
      #pragma unroll
      for (int m = 0; m < 4; ++m)
        #pragma unroll
        for (int n = 0; n < 4; ++n)
          acc[m][n] = __builtin_amdgcn_mfma_f32_16x16x32_bf16(
              af[m][kk], bf[n][kk], acc[m][n], 0, 0, 0);
    __syncthreads();
  }

  #pragma unroll
  for (int m = 0; m < 4; ++m) {
    #pragma unroll
    for (int n = 0; n < 4; ++n) {
      const long row0 = bm + wm + m*16 + g*4;
      const long col  = bn + wn + n*16 + r16;
      if constexpr (OUTMODE == 0) {
        unsigned short* Cb = (unsigned short*)Cout;
        const float sc = (col < scaleCols) ? scaleVal : 1.0f;
        #pragma unroll
        for (int r = 0; r < 4; ++r)
          Cb[(row0 + r) * N + col] = f2bf(acc[m][n][r] * sc);
      } else {
        float* Cf = (float*)Cout;
        const float bv = bias[col];
        #pragma unroll
        for (int r = 0; r < 4; ++r)
          Cf[(row0 + r) * N + col] = acc[m][n][r] + bv;
      }
    }
  }
}

// ---------------------------------------------------------------------------
// Flash attention v4: 32x32x16 MFMA, swapped operands; V^T via the R4-verified
// register-roundtrip + XOR-swizzled LDS (tr_read abandoned — unverifiable).
//  QK^T: S[kv][q] = mfma(Kfrag, Qfrag): lane owns q = lane&31; kv split with
//        partner lane (^32). Softmax lane-local; P->B-frags via cvt_pk+shfl32.
//  PV:   O^T[d][q] = mfma(V^T A-frag, P B-frag); V^T[d][j] in sVT32,
//        u16 elem j of row d at [d*128 + ((j>>3)^(d&15))*8 + (j&7)].
// Schedule per tile (ONE barrier): publish V^T[t] -> sync -> issue K-DMA[t+1]
//        + V-loads[t+1] -> QK^T -> softmax -> PV.
// Block: 128 q rows (4 waves x 32). KVBLK=128. LDS 64KB -> 2 blocks/CU.
__global__ __launch_bounds__(256)
void attn_fwd(const unsigned short* __restrict__ Qkv,
              unsigned short* __restrict__ O)
{
  __shared__ unsigned short sK[2][128 * 64];  // frag-major: (n*4+s)*512 + lane*8
  __shared__ unsigned int   sVT32[2][64 * 64];

  const int tid  = threadIdx.x;
  const int lane = tid & 63;
  const int w    = tid >> 6;
  const int l31  = lane & 31;
  const int hi   = lane >> 5;
  const int b  = blockIdx.z;
  const int h  = blockIdx.y;
  const int qb = blockIdx.x;                 // 16 q-blocks of 128 rows
  const long kvbase = (long)b * 2048;
  const int  ld = 3072;
  const long qrow = kvbase + qb * 128 + w * 32 + l31;  // this lane's q row

  // ---- Q fragments (B-operand): col q = l31, k(d) = s*16 + hi*8 + e ----
  v8s qf[4];
  #pragma unroll
  for (int s = 0; s < 4; ++s)
    qf[s] = *(const v8s*)(Qkv + qrow * ld + h*64 + s*16 + hi*8);

  // ---- staging source bases ----
  // K frag-major DMA: instr (w,i): lane -> K[w*32+l31][i*16+hi*8 ..+7]
  const unsigned short* KsrcB = Qkv + (kvbase + w*32 + l31) * ld + 1024 + h*64 + hi*8;
  // V vector loads (R4-verified): thread (w,lane) loads V[2*lane(+1)][w*16..+15]
  const int jp = lane, d0v = w * 16;
  const unsigned short* Vb = Qkv + 2048 + h*64 + d0v;

  v16f  oacc[2] = {};            // O^T[d][q]: dgrp 0/1
  float mrow = -__builtin_inff();
  float lsum = 0.0f;

  // ---- prologue: stage tile 0 ----
  v8s vreg[4];
  {
    char* dK = (char*)&sK[0][0] + w * 4096;
    #pragma unroll
    for (int i = 0; i < 4; ++i)
      gld_lds16(KsrcB + i * 16, dK + i * 1024);
    const unsigned short* vs = Vb + (kvbase + 2*jp) * ld;
    vreg[0] = *(const v8s*)vs;
    vreg[1] = *(const v8s*)(vs + 8);
    vreg[2] = *(const v8s*)(vs + ld);
    vreg[3] = *(const v8s*)(vs + ld + 8);
  }

  for (int t = 0; t < 16; ++t) {
    const unsigned short* sKc = &sK[t & 1][0];
    unsigned int* sVTc = &sVT32[t & 1][0];
    const unsigned short* sVTe = (const unsigned short*)sVTc;

    // ---- publish V^T[t] (drain this tile's loads first) ----
    asm volatile("s_waitcnt vmcnt(0)" ::: "memory");
    #pragma unroll
    for (int e = 0; e < 8; ++e) {
      int d = d0v + e;
      sVTc[d*64 + (((jp >> 2) ^ (d & 15)) << 2) + (jp & 3)] =
          ((unsigned)(unsigned short)vreg[2][e] << 16) | (unsigned short)vreg[0][e];
      d = d0v + 8 + e;
      sVTc[d*64 + (((jp >> 2) ^ (d & 15)) << 2) + (jp & 3)] =
          ((unsigned)(unsigned short)vreg[3][e] << 16) | (unsigned short)vreg[1][e];
    }
    __syncthreads();   // sK[t]/sVT[t] ready; prior reads of other buffer done

    // ---- issue staging for tile t+1 (lands during this tile's compute) ----
    if (t < 15) {
      const long kv0 = (long)(t + 1) * 128;
      char* dK = (char*)&sK[(t + 1) & 1][0] + w * 4096;
      #pragma unroll
      for (int i = 0; i < 4; ++i)
        gld_lds16(KsrcB + kv0 * ld + i * 16, dK + i * 1024);
      const unsigned short* vs = Vb + (kvbase + kv0 + 2*jp) * ld;
      vreg[0] = *(const v8s*)vs;
      vreg[1] = *(const v8s*)(vs + 8);
      vreg[2] = *(const v8s*)(vs + ld);
      vreg[3] = *(const v8s*)(vs + ld + 8);
    }

    // ---- QK^T: S[kv][q], 16 MFMA 32x32x16 ----
    v16f sacc[4] = {};
    __builtin_amdgcn_s_setprio(1);
    #pragma unroll
    for (int n = 0; n < 4; ++n)
      #pragma unroll
      for (int s = 0; s < 4; ++s) {
        v8s kf = *(const v8s*)(sKc + (n*4 + s) * 512 + lane * 8);
        sacc[n] = __builtin_amdgcn_mfma_f32_32x32x16_bf16(kf, qf[s], sacc[n], 0, 0, 0);
      }
    __builtin_amdgcn_s_setprio(0);

    // ---- lane-local softmax (exp2 domain), defer-max THR=8 ----
    float red[16];
    #pragma unroll
    for (int j = 0; j < 16; ++j)
      red[j] = fmaxf(fmaxf(sacc[0][j], sacc[1][j]),
                     fmaxf(sacc[2][j], sacc[3][j]));
    #pragma unroll
    for (int off = 8; off >= 1; off >>= 1)
      #pragma unroll
      for (int j = 0; j < 8; ++j)
        if (j < off) red[j] = fmaxf(red[j], red[j + off]);
    const float mx = fmaxf(red[0], __shfl_xor(red[0], 32));

    if (__any(mx - mrow > 8.0f)) {
      const float mnew  = fmaxf(mrow, mx);
      const float alpha = fexp2(mrow - mnew);
      mrow = mnew;
      lsum *= alpha;
      #pragma unroll
      for (int dg = 0; dg < 2; ++dg)
        #pragma unroll
        for (int j = 0; j < 16; ++j)
          oacc[dg][j] *= alpha;
    }
    {
      float ls0 = 0.f, ls1 = 0.f, ls2 = 0.f, ls3 = 0.f;
      #pragma unroll
      for (int j = 0; j < 16; ++j) {
        float p0 = fexp2(sacc[0][j] - mrow); sacc[0][j] = p0; ls0 += p0;
        float p1 = fexp2(sacc[1][j] - mrow); sacc[1][j] = p1; ls1 += p1;
        float p2 = fexp2(sacc[2][j] - mrow); sacc[2][j] = p2; ls2 += p2;
        float p3 = fexp2(sacc[3][j] - mrow); sacc[3][j] = p3; ls3 += p3;
      }
      lsum += (ls0 + ls1) + (ls2 + ls3);
    }

    // ---- P -> bf16 B-frags in-register (cvt_pk + xor-32 exchange) ----
    v8s pf[8];
    #pragma unroll
    for (int ks = 0; ks < 8; ++ks) {
      const int n = ks >> 1, r0 = (ks & 1) * 8;
      unsigned w0 = cvtpk(sacc[n][r0+0], sacc[n][r0+1]);
      unsigned w1 = cvtpk(sacc[n][r0+2], sacc[n][r0+3]);
      unsigned w2 = cvtpk(sacc[n][r0+4], sacc[n][r0+5]);
      unsigned w3 = cvtpk(sacc[n][r0+6], sacc[n][r0+7]);
      unsigned s0 = (unsigned)__shfl_xor((int)w0, 32);
      unsigned s1 = (unsigned)__shfl_xor((int)w1, 32);
      unsigned s2 = (unsigned)__shfl_xor((int)w2, 32);
      unsigned s3 = (unsigned)__shfl_xor((int)w3, 32);
      uint4 uu;
      uu.x = hi ? s2 : w0;   // kv_local b = 0,1
      uu.y = hi ? s3 : w1;   // b = 2,3
      uu.z = hi ? w2 : s0;   // b = 4,5
      uu.w = hi ? w3 : s1;   // b = 6,7
      pf[ks] = __builtin_bit_cast(v8s, uu);
    }

    // ---- PV: O^T[d][q] += V^T . P ; A-frag = V^T[d=dg*32+l31][ks*16+hi*8+b] ----
    __builtin_amdgcn_s_setprio(1);
    #pragma unroll
    for (int dg = 0; dg < 2; ++dg) {
      const int d = dg*32 + l31;
      const unsigned short* vrow = sVTe + d*128;
      #pragma unroll
      for (int ks = 0; ks < 8; ++ks) {
        v8s vf = *(const v8s*)(vrow + (((ks*2 + hi) ^ (d & 15)) << 3));
        oacc[dg] = __builtin_amdgcn_mfma_f32_32x32x16_bf16(vf, pf[ks], oacc[dg], 0, 0, 0);
      }
    }
    __builtin_amdgcn_s_setprio(0);
  }

  // ---- epilogue: O[q][d] = oacc/lsum_total ----
  const float tot = lsum + __shfl_xor(lsum, 32);
  const float inv = 1.0f / tot;
  #pragma unroll
  for (int dg = 0; dg < 2; ++dg) {
    #pragma unroll
    for (int rq = 0; rq < 4; ++rq) {
      ushort4 pk4;
      pk4.x = f2bf(oacc[dg][rq*4 + 0] * inv);
      pk4.y = f2bf(oacc[dg][rq*4 + 1] * inv);
      pk4.z = f2bf(oacc[dg][rq*4 + 2] * inv);
      pk4.w = f2bf(oacc[dg][rq*4 + 3] * inv);
      const int d0 = dg*32 + rq*8 + hi*4;   // d = d0 + (reg&3)
      *(ushort4*)(O + qrow * 1024 + h*64 + d0) = pk4;
    }
  }
}

// ---------------------------------------------------------------------------
extern "C" void kernel_launch(void* const* d_in, const int* in_sizes, int n_in,
                              void* d_out, int out_size, void* d_ws, size_t ws_size,
                              hipStream_t stream)
{
  const float* x  = (const float*)d_in[0];
  const float* wq = (const float*)d_in[1];
  const float* wk = (const float*)d_in[2];
  const float* wv = (const float*)d_in[3];
  const float* wo = (const float*)d_in[4];
  const float* bo = (const float*)d_in[5];

  unsigned short* Xb   = (unsigned short*)d_ws;              // 8192*1024
  unsigned short* Wqkv = Xb   + (size_t)8192 * 1024;         // 3072*1024
  unsigned short* Wob  = Wqkv + (size_t)3072 * 1024;         // 1024*1024
  unsigned short* Qkv  = Wob  + (size_t)1024 * 1024;         // 8192*3072
  unsigned short* Obuf = Xb;                                 // reuse (Xb dead)
  float* out = (float*)d_out;

  cvt_f32_bf16<<<2048, 256, 0, stream>>>(x,  Xb,   8192 * 1024 / 4);
  cvt_f32_bf16<<<512,  256, 0, stream>>>(wq, Wqkv,              1024 * 1024 / 4);
  cvt_f32_bf16<<<512,  256, 0, stream>>>(wk, Wqkv + 1024*1024,  1024 * 1024 / 4);
  cvt_f32_bf16<<<512,  256, 0, stream>>>(wv, Wqkv + 2*1024*1024,1024 * 1024 / 4);
  cvt_f32_bf16<<<512,  256, 0, stream>>>(wo, Wob,               1024 * 1024 / 4);

  // QKV: M=8192 N=3072 K=1024; Q cols scaled by 0.125 * log2(e)  (exp2 domain)
  gemm_bt<0><<<dim3(24, 64), 256, 0, stream>>>(Xb, Wqkv, Qkv, nullptr,
                                               8192, 3072, 1024, 1024,
                                               0.18033688011112042f);
  attn_fwd<<<dim3(16, 16, 4), 256, 0, stream>>>(Qkv, Obuf);
  gemm_bt<1><<<dim3(8, 64), 256, 0, stream>>>(Obuf, Wob, out, bo,
                                              8192, 1024, 1024, 0, 1.0f);
}